// Round 12
// baseline (98.812 us; speedup 1.0000x reference)
//
#include <hip/hip_runtime.h>
#include <cfloat>

typedef unsigned short u16;
typedef unsigned int u32;
typedef u16   u16x4 __attribute__((ext_vector_type(4)));
typedef float f32x4 __attribute__((ext_vector_type(4)));
typedef _Float16 f16x8 __attribute__((ext_vector_type(8)));

#define GL2LDS(gp, lp) __builtin_amdgcn_global_load_lds(                      \
    (const __attribute__((address_space(1))) void*)(gp),                      \
    (__attribute__((address_space(3))) void*)(lp), 16, 0, 0)

#define FENCE asm volatile("" ::: "memory")
#define RBAR  do { FENCE; __builtin_amdgcn_s_barrier(); FENCE; } while (0)
#define LGKM0 do { asm volatile("s_waitcnt lgkmcnt(0)" ::: "memory");         \
                   __builtin_amdgcn_sched_barrier(0); } while (0)

// lexicographic (value, index) less — matches argmin lowest-index tie-break
__device__ __forceinline__ bool vless(float v, int i, float v2, int i2) {
  return v < v2 || (v == v2 && i < i2);
}

// monotonic float->uint map (order-preserving for all finite floats)
__device__ __forceinline__ u32 fmono(float f) {
  u32 u = __float_as_uint(f);
  return u ^ (0x80000000u | (u32)((int)u >> 31));
}
__device__ __forceinline__ float fmono_inv(u32 m) {
  u32 u = (m & 0x80000000u) ? (m ^ 0x80000000u) : ~m;
  return __uint_as_float(u);
}

// ---------------------------------------------------------------------------
// Pretile a [R,512] fp32 matrix into FRAGMENT-MAJOR f16 panels (+c2 +copy).
// Panel unit = (tile of 256 rows, 64-k step s) = 32 KB = 2 halves x 16 KB.
// Half = 128 rows; 16 fragments of 1 KB: frag (rb,h) holds rows rb*16..+15,
// k h*32..+31; lane (kgrp*16+lrow) holds row lrow's k kgrp*8..+7 at lane*16
// — exact MFMA operand order: gl2lds linear, ds_read at base+lane*16.
__global__ __launch_bounds__(128) void vq_prep(
    const float* __restrict__ src, u16* __restrict__ pan,
    float* __restrict__ sq, float* __restrict__ copy_out) {
  __shared__ float red[2];
  const int row_g = blockIdx.x;
  const int t = threadIdx.x;             // 0..127, 4 floats each
  float4 v = reinterpret_cast<const float4*>(src + (size_t)row_g * 512)[t];
  if (copy_out)
    reinterpret_cast<float4*>(copy_out + (size_t)row_g * 512)[t] = v;
  float f[4] = {v.x, v.y, v.z, v.w};
  u16 q[4];
  #pragma unroll
  for (int i = 0; i < 4; ++i)
    q[i] = __builtin_bit_cast(u16, (_Float16)f[i]);   // RNE
  const int d = t * 4;
  const int tile = row_g >> 8, r = row_g & 255;
  const int half = r >> 7, rr = r & 127, rb = rr >> 4, lrow = rr & 15;
  const int s = d >> 6, kk = d & 63, h = kk >> 5;
  const int kgrp = (kk & 31) >> 3, e = kk & 7;
  const size_t off = ((size_t)(tile * 8 + s)) * 32768 + half * 16384 +
      (size_t)((rb * 2 + h) * 1024 + (kgrp * 16 + lrow) * 16 + e * 2);
  u16x4 tq = {q[0], q[1], q[2], q[3]};
  *reinterpret_cast<u16x4*>((char*)pan + off) = tq;
  if (sq) {
    float ssum = v.x*v.x + v.y*v.y + v.z*v.z + v.w*v.w;
    #pragma unroll
    for (int m = 1; m < 64; m <<= 1) ssum += __shfl_xor(ssum, m);
    if ((t & 63) == 0) red[t >> 6] = ssum;
    __syncthreads();
    if (t == 0) sq[row_g] = red[0] + red[1];
  }
}

// ---------------------------------------------------------------------------
// Screening GEMM, m201-faithful 8-phase port (single f16, fragment-major).
// Tile 256x256, BK=64, 8 waves (2x4), per-wave 128x64 (acc 8x4 f32x4).
// Per K-tile: 4 quadrant phases, each { ds_read frags | stage one 16KB
// half-tile (2 gl2lds) | s_barrier | lgkmcnt(0) | setprio 16 MFMA | s_barrier }
// vmcnt(0) ONCE per K-tile (phase-3 end). LDS 128 KB dbuf; reads at
// base+lane*16 -> conflict-free. score = c2[col] - 2*dot.
template <int PANEL_A>
__global__ __launch_bounds__(512, 2) void vq_gemm(
    const float* __restrict__ X,
    const u16* __restrict__ Apan, const u16* __restrict__ Bpan,
    const float* __restrict__ c2,
    float4* __restrict__ part, int nnt) {
  __shared__ u16 sA[2][16384], sB[2][16384];   // [dbuf][2 halves x 16KB]
  const int tid = threadIdx.x;
  const int lane = tid & 63, wid = tid >> 6;   // 8 waves
  const int wm = wid >> 2, wn = wid & 3;       // 2 x 4
  const int nwg = gridDim.x;
  const int bid = blockIdx.x;
  const int swb = (bid & 7) * (nwg >> 3) + (bid >> 3);  // XCD band swizzle
  const int mtile = swb / nnt, ntile = swb % nnt;
  const int lrow = lane & 15, kgrp = lane >> 4;
  f32x4 acc[8][4] = {};

  const char* gA = (const char*)Apan + (size_t)mtile * 8 * 32768;
  const char* gB = (const char*)Bpan + (size_t)ntile * 8 * 32768;
  const int loff = wid * 1024 + lane * 16;     // wave-uniform base + lane*16

  // stage one 16 KB half-tile: ht 0/1 = A halves, 2/3 = B halves
  auto stageHT = [&](int kt, int buf, int ht) {
    const char* g; char* d;
    if (ht < 2) { g = gA + (size_t)kt * 32768 + ht * 16384;
                  d = (char*)sA[buf] + ht * 16384; }
    else        { g = gB + (size_t)kt * 32768 + (ht - 2) * 16384;
                  d = (char*)sB[buf] + (ht - 2) * 16384; }
    GL2LDS(g + loff, d + loff);
    GL2LDS(g + 8192 + loff, d + 8192 + loff);
  };
  // fallback: convert 128-row half of X K-tile into LDS (correctness path)
  auto cvtA = [&](int kt, int buf, int half) {
    #pragma unroll
    for (int p = 0; p < 4; ++p) {
      const int idx = tid + p * 512;           // 2048 chunks of 4 k
      const int r = idx >> 4, c0 = (idx & 15) * 4;
      const float4 v = *reinterpret_cast<const float4*>(
          X + ((size_t)(mtile * 256 + half * 128 + r)) * 512 + kt * 64 + c0);
      float f[4] = {v.x, v.y, v.z, v.w};
      u16 q[4];
      #pragma unroll
      for (int i = 0; i < 4; ++i)
        q[i] = __builtin_bit_cast(u16, (_Float16)f[i]);
      const int rb = r >> 4, lr = r & 15, h = c0 >> 5;
      const int kg = (c0 & 31) >> 3, e = c0 & 7;
      u16x4 tq = {q[0], q[1], q[2], q[3]};
      *reinterpret_cast<u16x4*>((char*)sA[buf] + half * 16384 +
          (rb * 2 + h) * 1024 + (kg * 16 + lr) * 16 + e * 2) = tq;
    }
  };

  f16x8 a[8], b0[4], b1[4];
  auto readA = [&](int buf, int rh) {          // 8 frags: (t,h)
    const char* base = (const char*)sA[buf] + wm * 16384;
    #pragma unroll
    for (int t = 0; t < 4; ++t)
      #pragma unroll
      for (int h = 0; h < 2; ++h)
        a[t * 2 + h] = *reinterpret_cast<const f16x8*>(
            base + ((rh * 4 + t) * 2 + h) * 1024 + lane * 16);
  };
  auto readB = [&](int buf, int ch, f16x8* b) { // 4 frags: (u,h)
    const char* base = (const char*)sB[buf] + (wn >> 1) * 16384;
    #pragma unroll
    for (int u = 0; u < 2; ++u)
      #pragma unroll
      for (int h = 0; h < 2; ++h)
        b[u * 2 + h] = *reinterpret_cast<const f16x8*>(
            base + (((wn & 1) * 4 + ch * 2 + u) * 2 + h) * 1024 + lane * 16);
  };
  auto mfmaQ = [&](const f16x8* b, int rh, int ch) {  // 16 MFMA
    __builtin_amdgcn_s_setprio(1);
    #pragma unroll
    for (int t = 0; t < 4; ++t)
      #pragma unroll
      for (int u = 0; u < 2; ++u)
        #pragma unroll
        for (int h = 0; h < 2; ++h)
          acc[rh * 4 + t][ch * 2 + u] = __builtin_amdgcn_mfma_f32_16x16x32_f16(
              a[t * 2 + h], b[u * 2 + h], acc[rh * 4 + t][ch * 2 + u], 0, 0, 0);
    __builtin_amdgcn_s_setprio(0);
  };

  // ---- prologue: stage K-tile 0 fully, drain, barrier
  if constexpr (PANEL_A) { stageHT(0, 0, 0); stageHT(0, 0, 1); }
  else { cvtA(0, 0, 0); cvtA(0, 0, 1); }
  stageHT(0, 0, 2); stageHT(0, 0, 3);
  asm volatile("s_waitcnt vmcnt(0) lgkmcnt(0)" ::: "memory");
  RBAR;

  int buf = 0;
  #pragma unroll 1
  for (int kt = 0; kt < 8; ++kt) {
    const int nb = buf ^ 1;
    const bool more = (kt < 7);
    // ---- p0 : Q(0,0)    [stage A-h0']
    readA(buf, 0);
    readB(buf, 0, b0);
    if (more) { if constexpr (PANEL_A) stageHT(kt + 1, nb, 0); else cvtA(kt + 1, nb, 0); }
    RBAR; LGKM0;
    mfmaQ(b0, 0, 0);
    RBAR;
    // ---- p1 : Q(0,1)    [stage A-h1']
    readB(buf, 1, b1);
    if (more) { if constexpr (PANEL_A) stageHT(kt + 1, nb, 1); else cvtA(kt + 1, nb, 1); }
    RBAR; LGKM0;
    mfmaQ(b1, 0, 1);
    RBAR;
    // ---- p2 : Q(1,0)    [stage B-h0']
    readA(buf, 1);
    if (more) stageHT(kt + 1, nb, 2);
    RBAR; LGKM0;
    mfmaQ(b0, 1, 0);
    RBAR;
    // ---- p3 : Q(1,1)    [stage B-h1']
    if (more) stageHT(kt + 1, nb, 3);
    RBAR; LGKM0;
    mfmaQ(b1, 1, 1);
    if (more) {
      if constexpr (PANEL_A)
        asm volatile("s_waitcnt vmcnt(0)" ::: "memory");
      else
        asm volatile("s_waitcnt vmcnt(0) lgkmcnt(0)" ::: "memory");
    }
    RBAR;
    buf ^= 1;
  }

  // ---- epilogue: per-row TOP-2 over this wave's 64 cols via packed keys.
  // key = (monotonic(score) & ~0x7FF) | col; quantization absorbed by the
  // final margin (1.0).
  float c2v[4];
  #pragma unroll
  for (int j = 0; j < 4; ++j) c2v[j] = c2[ntile * 256 + wn * 64 + j * 16 + lrow];
  #pragma unroll
  for (int i = 0; i < 8; ++i) {
    #pragma unroll
    for (int jj = 0; jj < 4; ++jj) {
      u32 k1 = 0xFFFFFFFFu, k2 = 0xFFFFFFFFu;
      #pragma unroll
      for (int j = 0; j < 4; ++j) {
        const float sc = c2v[j] - 2.0f * acc[i][j][jj];
        const u32 col = (u32)(ntile * 256 + wn * 64 + j * 16 + lrow);
        const u32 k = (fmono(sc) & 0xFFFFF800u) | col;
        if (k < k1) { k2 = k1; k1 = k; } else if (k < k2) { k2 = k; }
      }
      #pragma unroll
      for (int m = 1; m < 16; m <<= 1) {
        const u32 ok1 = (u32)__shfl_xor((int)k1, m);
        const u32 ok2 = (u32)__shfl_xor((int)k2, m);
        const u32 lo = min(k1, ok1), hi = max(k1, ok1);
        k1 = lo;
        k2 = min(hi, min(k2, ok2));
      }
      if (lrow == 0) {
        const int row = mtile * 256 + wm * 128 + i * 16 + kgrp * 4 + jj;
        part[(size_t)row * 32 + (ntile * 4 + wn)] =
            make_float4(fmono_inv(k1 & 0xFFFFF800u), __int_as_float((int)(k1 & 0x7FFu)),
                        fmono_inv(k2 & 0xFFFFF800u), __int_as_float((int)(k2 & 0x7FFu)));
      }
    }
  }
}

// ---------------------------------------------------------------------------
// Final: global approx argmin over 64 stored candidates/row; margin-flag;
// exact double-precision refine when >1 candidate within margin; outputs.
__global__ __launch_bounds__(256) void vq_final(
    const float* __restrict__ X, const float* __restrict__ CB,
    const float4* __restrict__ part,
    float* __restrict__ out0, float* __restrict__ out1, float* __restrict__ out2) {
  const int row = blockIdx.x * 4 + (threadIdx.x >> 6);
  const int l = threadIdx.x & 63;
  const float4 p = part[(size_t)row * 32 + (l >> 1)];
  const float v = (l & 1) ? p.z : p.x;
  const int ci = __float_as_int((l & 1) ? p.w : p.y);
  float rv = v; int ri = ci;
  #pragma unroll
  for (int m = 1; m < 64; m <<= 1) {
    const float ov = __shfl_xor(rv, m);
    const int oi = __shfl_xor(ri, m);
    if (vless(ov, oi, rv, ri)) { rv = ov; ri = oi; }
  }
  int idx;
  unsigned long long mask = __ballot(v <= rv + 1.0f);   // margin (f16 + key quant)
  if (__popcll(mask) == 1) {
    idx = ri;                                            // certain winner
  } else {
    float xr[8];
    #pragma unroll
    for (int e = 0; e < 8; ++e) xr[e] = X[(size_t)row * 512 + l + e * 64];
    double bd = 1e300; int bi = 0x7fffffff;
    while (mask) {
      const int sl = __ffsll((long long)mask) - 1;
      mask &= mask - 1;
      const int cidx = __shfl(ci, sl);
      double accd = 0.0;
      #pragma unroll
      for (int e = 0; e < 8; ++e) {
        const double dd = (double)xr[e] - (double)CB[(size_t)cidx * 512 + l + e * 64];
        accd += dd * dd;
      }
      #pragma unroll
      for (int m = 1; m < 64; m <<= 1) accd += __shfl_xor(accd, m);
      if (accd < bd || (accd == bd && cidx < bi)) { bd = accd; bi = cidx; }
    }
    idx = bi;
  }
  const float4* xr4 = reinterpret_cast<const float4*>(X + (size_t)row * 512);
  const float4* cr4 = reinterpret_cast<const float4*>(CB + (size_t)idx * 512);
  float4* q  = reinterpret_cast<float4*>(out0 + (size_t)row * 512);
  float4* ls = reinterpret_cast<float4*>(out1 + (size_t)row * 512);
  #pragma unroll
  for (int pp = 0; pp < 2; ++pp) {
    const int e = l + 64 * pp;
    const float4 xv = xr4[e], cv = cr4[e];
    float4 d4, qv, lv;
    d4.x = cv.x - xv.x; d4.y = cv.y - xv.y; d4.z = cv.z - xv.z; d4.w = cv.w - xv.w;
    qv.x = xv.x + d4.x; qv.y = xv.y + d4.y; qv.z = xv.z + d4.z; qv.w = xv.w + d4.w;
    lv.x = d4.x * d4.x; lv.y = d4.y * d4.y; lv.z = d4.z * d4.z; lv.w = d4.w * d4.w;
    q[e] = qv; ls[e] = lv;
  }
  if (l == 0) out2[row] = (float)idx;
}

extern "C" void kernel_launch(void* const* d_in, const int* in_sizes, int n_in,
                              void* d_out, int out_size, void* d_ws, size_t ws_size,
                              hipStream_t stream) {
  const float* X  = (const float*)d_in[0];   // [M,512] fp32
  const float* CB = (const float*)d_in[1];   // [K,512] fp32
  const int D = 512;
  const int M = in_sizes[0] / D;             // 16384
  const int K = in_sizes[1] / D;             // 2048
  float* out0 = (float*)d_out;               // quantized_ste [M,512]
  float* out1 = out0 + (size_t)M * D;        // loss          [M,512]
  float* out2 = out1 + (size_t)M * D;        // nn_idx (as f32) [M]
  float* out3 = out2 + M;                    // codebook copy [K,512]

  char* ws = (char*)d_ws;
  size_t off = 0;
  u16* Bpan = (u16*)(ws + off); off += (size_t)K * D * 2;     // f16 fragment panels
  float* c2 = (float*)(ws + off); off += (size_t)K * 4;
  float4* part = (float4*)(ws + off); off += (size_t)M * 32 * 16;
  u16* Apan = (u16*)(ws + off);
  const size_t need_big = off + (size_t)M * D * 2;
  const bool big = (ws_size >= need_big);

  vq_prep<<<K, 128, 0, stream>>>(CB, Bpan, c2, out3);
  const int nmt = M / 256, nnt = K / 256;                     // 64 x 8
  const int nwg = nmt * nnt;                                  // 512
  if (big) {
    vq_prep<<<M, 128, 0, stream>>>(X, Apan, nullptr, nullptr);
    vq_gemm<1><<<nwg, 512, 0, stream>>>(X, Apan, Bpan, c2, part, nnt);
  } else {
    vq_gemm<0><<<nwg, 512, 0, stream>>>(X, nullptr, Bpan, c2, part, nnt);
  }
  vq_final<<<M / 4, 256, 0, stream>>>(X, CB, part, out0, out1, out2);
}

// Round 13
// 98.645 us; speedup vs baseline: 1.0017x; 1.0017x over previous
//
#include <hip/hip_runtime.h>
#include <cfloat>

typedef unsigned short u16;
typedef unsigned int u32;
typedef u16   u16x4 __attribute__((ext_vector_type(4)));
typedef float f32x4 __attribute__((ext_vector_type(4)));
typedef _Float16 f16x8 __attribute__((ext_vector_type(8)));

#define GL2LDS(gp, lp) __builtin_amdgcn_global_load_lds(                      \
    (const __attribute__((address_space(1))) void*)(gp),                      \
    (__attribute__((address_space(3))) void*)(lp), 16, 0, 0)

#define FENCE asm volatile("" ::: "memory")
#define RBAR  do { FENCE; __builtin_amdgcn_s_barrier(); FENCE; } while (0)
#define LGKM0 do { asm volatile("s_waitcnt lgkmcnt(0)" ::: "memory");         \
                   __builtin_amdgcn_sched_barrier(0); } while (0)

// lexicographic (value, index) less — matches argmin lowest-index tie-break
__device__ __forceinline__ bool vless(float v, int i, float v2, int i2) {
  return v < v2 || (v == v2 && i < i2);
}

// monotonic float->uint map (order-preserving for all finite floats)
__device__ __forceinline__ u32 fmono(float f) {
  u32 u = __float_as_uint(f);
  return u ^ (0x80000000u | (u32)((int)u >> 31));
}
__device__ __forceinline__ float fmono_inv(u32 m) {
  u32 u = (m & 0x80000000u) ? (m ^ 0x80000000u) : ~m;
  return __uint_as_float(u);
}

// ---------------------------------------------------------------------------
// Pretile a [R,512] fp32 matrix into K-HALF-MAJOR fragment panels (+c2+copy).
// Panel unit = (tile of 256 rows, 64-k step s) = 32 KB = [kh0:16KB][kh1:16KB].
// K-half = 256 rows x 32 k as 16 fragments of 1 KB (frag rb = rows rb*16..+15);
// lane (kgrp*16+lrow) holds row lrow's k kgrp*8..+7 at frag + lane*16 — exact
// MFMA operand order: gl2lds linear, ds_read at base+lane*16 (conflict-free).
__global__ __launch_bounds__(128) void vq_prep(
    const float* __restrict__ src, u16* __restrict__ pan,
    float* __restrict__ sq, float* __restrict__ copy_out) {
  __shared__ float red[2];
  const int row_g = blockIdx.x;
  const int t = threadIdx.x;             // 0..127, 4 floats each
  float4 v = reinterpret_cast<const float4*>(src + (size_t)row_g * 512)[t];
  if (copy_out)
    reinterpret_cast<float4*>(copy_out + (size_t)row_g * 512)[t] = v;
  float f[4] = {v.x, v.y, v.z, v.w};
  u16 q[4];
  #pragma unroll
  for (int i = 0; i < 4; ++i)
    q[i] = __builtin_bit_cast(u16, (_Float16)f[i]);   // RNE
  const int d = t * 4;
  const int tile = row_g >> 8, r = row_g & 255;
  const int rb = r >> 4, lrow = r & 15;
  const int s = d >> 6, kk = d & 63, kh = kk >> 5;
  const int kg = (kk & 31) >> 3, e = kk & 7;
  const size_t off = ((size_t)(tile * 8 + s)) * 32768 + kh * 16384 +
      (size_t)(rb * 1024 + (kg * 16 + lrow) * 16 + e * 2);
  u16x4 tq = {q[0], q[1], q[2], q[3]};
  *reinterpret_cast<u16x4*>((char*)pan + off) = tq;
  if (sq) {
    float ssum = v.x*v.x + v.y*v.y + v.z*v.z + v.w*v.w;
    #pragma unroll
    for (int m = 1; m < 64; m <<= 1) ssum += __shfl_xor(ssum, m);
    if ((t & 63) == 0) red[t >> 6] = ssum;
    __syncthreads();
    if (t == 0) sq[row_g] = red[0] + red[1];
  }
}

// ---------------------------------------------------------------------------
// Screening GEMM: K-split phases with COUNTED vmcnt (T3+T4, never drain0).
// Tile 256x256, BK=64, 8 waves (2x4), per-wave 128x64 (acc 8x4 f32x4).
// Per K-tile: 2 phases (one per k-half). Phase kh:
//   { 12 ds_read (8 A + 4 B frags of kh) | stage next tile's kh half-tiles
//     (4 gl2lds) | s_barrier | lgkmcnt(0) | setprio 32 MFMA | vmcnt(4)
//     | s_barrier }
// Ledger: 8 loads outstanding at every phase end -> vmcnt(4) retires exactly
// the half-tiles the next phase consumes; per-wave count + barrier = sound.
// score = c2[col] - 2*dot (x2 row-constant, dropped for argmin).
template <int PANEL_A>
__global__ __launch_bounds__(512, 2) void vq_gemm(
    const float* __restrict__ X,
    const u16* __restrict__ Apan, const u16* __restrict__ Bpan,
    const float* __restrict__ c2,
    float4* __restrict__ part, int nnt) {
  __shared__ u16 sA[2][16384], sB[2][16384];   // [dbuf][kh0|kh1], 128 KB
  const int tid = threadIdx.x;
  const int lane = tid & 63, wid = tid >> 6;   // 8 waves
  const int wm = wid >> 2, wn = wid & 3;       // 2 x 4
  const int nwg = gridDim.x;
  const int bid = blockIdx.x;
  const int swb = (bid & 7) * (nwg >> 3) + (bid >> 3);  // XCD band swizzle
  const int mtile = swb / nnt, ntile = swb % nnt;
  const int lrow = lane & 15, kgrp = lane >> 4;
  f32x4 acc[8][4] = {};

  const char* gA = (const char*)Apan + (size_t)mtile * 8 * 32768;
  const char* gB = (const char*)Bpan + (size_t)ntile * 8 * 32768;

  // stage one 16 KB k-half of next tile: 2 gl2lds per thread, linear
  auto stageHT = [&](const char* gpan, int kt2, char* dstbuf, int kh) {
    const char* g = gpan + (size_t)kt2 * 32768 + kh * 16384;
    char* d = dstbuf + kh * 16384;
    const int o = wid * 1024 + lane * 16;
    GL2LDS(g + o, d + o);
    GL2LDS(g + 8192 + o, d + 8192 + o);
  };
  // fallback: convert one k-half of X tile into LDS (correctness path)
  auto cvtA = [&](int kt2, int nb2, int kh2, u16* dstbuf) {
    #pragma unroll
    for (int p = 0; p < 4; ++p) {
      const int idx = tid + p * 512;           // 2048 chunks of 4 k
      const int r = idx >> 3, c0 = (idx & 7) * 4;
      const float4 v = *reinterpret_cast<const float4*>(
          X + ((size_t)(mtile * 256 + r)) * 512 + kt2 * 64 + kh2 * 32 + c0);
      float f[4] = {v.x, v.y, v.z, v.w};
      u16 q[4];
      #pragma unroll
      for (int i = 0; i < 4; ++i)
        q[i] = __builtin_bit_cast(u16, (_Float16)f[i]);
      const int rb = r >> 4, lr = r & 15, kg = c0 >> 3, e = c0 & 7;
      u16x4 tq = {q[0], q[1], q[2], q[3]};
      *reinterpret_cast<u16x4*>((char*)dstbuf + kh2 * 16384 +
          rb * 1024 + (kg * 16 + lr) * 16 + e * 2) = tq;
    }
    (void)nb2;
  };

  auto phase = [&](int buf, int nb, int kt, int kh, bool more) {
    // ---- 12 ds_reads for this k-half (issued, not waited)
    f16x8 a[8], b[4];
    const char* Ab = (const char*)sA[buf] + kh * 16384 + wm * 8192;
    #pragma unroll
    for (int t = 0; t < 8; ++t)
      a[t] = *reinterpret_cast<const f16x8*>(Ab + t * 1024 + lane * 16);
    const char* Bb = (const char*)sB[buf] + kh * 16384 + wn * 4096;
    #pragma unroll
    for (int u = 0; u < 4; ++u)
      b[u] = *reinterpret_cast<const f16x8*>(Bb + u * 1024 + lane * 16);
    // ---- stage next tile's same k-half
    if (more) {
      if constexpr (PANEL_A) stageHT(gA, kt + 1, (char*)sA[nb], kh);
      else cvtA(kt + 1, nb, kh, sA[nb]);
      stageHT(gB, kt + 1, (char*)sB[nb], kh);
    }
    RBAR;
    LGKM0;
    __builtin_amdgcn_s_setprio(1);
    #pragma unroll
    for (int i = 0; i < 8; ++i)
      #pragma unroll
      for (int j = 0; j < 4; ++j)
        acc[i][j] = __builtin_amdgcn_mfma_f32_16x16x32_f16(a[i], b[j], acc[i][j], 0, 0, 0);
    __builtin_amdgcn_s_setprio(0);
    if (more) {
      if constexpr (PANEL_A)
        asm volatile("s_waitcnt vmcnt(4)" ::: "memory");   // counted: 4 stay in flight
      else
        asm volatile("s_waitcnt vmcnt(0) lgkmcnt(0)" ::: "memory");
    } else if (kh == 0) {
      asm volatile("s_waitcnt vmcnt(0)" ::: "memory");     // epilogue drain (last tile)
    }
    RBAR;
  };

  // ---- prologue: stage K-tile 0 (both k-halves), counted wait
  if constexpr (PANEL_A) {
    stageHT(gA, 0, (char*)sA[0], 0); stageHT(gB, 0, (char*)sB[0], 0);
    stageHT(gA, 0, (char*)sA[0], 1); stageHT(gB, 0, (char*)sB[0], 1);
    asm volatile("s_waitcnt vmcnt(4)" ::: "memory");  // kh0 halves landed
  } else {
    cvtA(0, 0, 0, sA[0]); cvtA(0, 0, 1, sA[0]);
    stageHT(gB, 0, (char*)sB[0], 0); stageHT(gB, 0, (char*)sB[0], 1);
    asm volatile("s_waitcnt vmcnt(0) lgkmcnt(0)" ::: "memory");
  }
  RBAR;

  int buf = 0;
  #pragma unroll 1
  for (int kt = 0; kt < 8; ++kt) {
    const int nb = buf ^ 1;
    const bool more = (kt < 7);
    phase(buf, nb, kt, 0, more);
    phase(buf, nb, kt, 1, more);
    buf ^= 1;
  }

  // ---- epilogue: per-row TOP-2 over this wave's 64 cols via packed keys.
  // key = (monotonic(score) & ~0x7FF) | col; quantization absorbed by the
  // final margin (1.0).
  float c2v[4];
  #pragma unroll
  for (int j = 0; j < 4; ++j) c2v[j] = c2[ntile * 256 + wn * 64 + j * 16 + lrow];
  #pragma unroll
  for (int i = 0; i < 8; ++i) {
    #pragma unroll
    for (int jj = 0; jj < 4; ++jj) {
      u32 k1 = 0xFFFFFFFFu, k2 = 0xFFFFFFFFu;
      #pragma unroll
      for (int j = 0; j < 4; ++j) {
        const float sc = c2v[j] - 2.0f * acc[i][j][jj];
        const u32 col = (u32)(ntile * 256 + wn * 64 + j * 16 + lrow);
        const u32 k = (fmono(sc) & 0xFFFFF800u) | col;
        if (k < k1) { k2 = k1; k1 = k; } else if (k < k2) { k2 = k; }
      }
      #pragma unroll
      for (int m = 1; m < 16; m <<= 1) {
        const u32 ok1 = (u32)__shfl_xor((int)k1, m);
        const u32 ok2 = (u32)__shfl_xor((int)k2, m);
        const u32 lo = min(k1, ok1), hi = max(k1, ok1);
        k1 = lo;
        k2 = min(hi, min(k2, ok2));
      }
      if (lrow == 0) {
        const int row = mtile * 256 + wm * 128 + i * 16 + kgrp * 4 + jj;
        part[(size_t)row * 32 + (ntile * 4 + wn)] =
            make_float4(fmono_inv(k1 & 0xFFFFF800u), __int_as_float((int)(k1 & 0x7FFu)),
                        fmono_inv(k2 & 0xFFFFF800u), __int_as_float((int)(k2 & 0x7FFu)));
      }
    }
  }
}

// ---------------------------------------------------------------------------
// Final: global approx argmin over 64 stored candidates/row; margin-flag;
// exact double-precision refine when >1 candidate within margin; outputs.
__global__ __launch_bounds__(256) void vq_final(
    const float* __restrict__ X, const float* __restrict__ CB,
    const float4* __restrict__ part,
    float* __restrict__ out0, float* __restrict__ out1, float* __restrict__ out2) {
  const int row = blockIdx.x * 4 + (threadIdx.x >> 6);
  const int l = threadIdx.x & 63;
  const float4 p = part[(size_t)row * 32 + (l >> 1)];
  const float v = (l & 1) ? p.z : p.x;
  const int ci = __float_as_int((l & 1) ? p.w : p.y);
  float rv = v; int ri = ci;
  #pragma unroll
  for (int m = 1; m < 64; m <<= 1) {
    const float ov = __shfl_xor(rv, m);
    const int oi = __shfl_xor(ri, m);
    if (vless(ov, oi, rv, ri)) { rv = ov; ri = oi; }
  }
  int idx;
  unsigned long long mask = __ballot(v <= rv + 1.0f);   // margin (f16 + key quant)
  if (__popcll(mask) == 1) {
    idx = ri;                                            // certain winner
  } else {
    float xr[8];
    #pragma unroll
    for (int e = 0; e < 8; ++e) xr[e] = X[(size_t)row * 512 + l + e * 64];
    double bd = 1e300; int bi = 0x7fffffff;
    while (mask) {
      const int sl = __ffsll((long long)mask) - 1;
      mask &= mask - 1;
      const int cidx = __shfl(ci, sl);
      double accd = 0.0;
      #pragma unroll
      for (int e = 0; e < 8; ++e) {
        const double dd = (double)xr[e] - (double)CB[(size_t)cidx * 512 + l + e * 64];
        accd += dd * dd;
      }
      #pragma unroll
      for (int m = 1; m < 64; m <<= 1) accd += __shfl_xor(accd, m);
      if (accd < bd || (accd == bd && cidx < bi)) { bd = accd; bi = cidx; }
    }
    idx = bi;
  }
  const float4* xr4 = reinterpret_cast<const float4*>(X + (size_t)row * 512);
  const float4* cr4 = reinterpret_cast<const float4*>(CB + (size_t)idx * 512);
  float4* q  = reinterpret_cast<float4*>(out0 + (size_t)row * 512);
  float4* ls = reinterpret_cast<float4*>(out1 + (size_t)row * 512);
  #pragma unroll
  for (int pp = 0; pp < 2; ++pp) {
    const int e = l + 64 * pp;
    const float4 xv = xr4[e], cv = cr4[e];
    float4 d4, qv, lv;
    d4.x = cv.x - xv.x; d4.y = cv.y - xv.y; d4.z = cv.z - xv.z; d4.w = cv.w - xv.w;
    qv.x = xv.x + d4.x; qv.y = xv.y + d4.y; qv.z = xv.z + d4.z; qv.w = xv.w + d4.w;
    lv.x = d4.x * d4.x; lv.y = d4.y * d4.y; lv.z = d4.z * d4.z; lv.w = d4.w * d4.w;
    q[e] = qv; ls[e] = lv;
  }
  if (l == 0) out2[row] = (float)idx;
}

extern "C" void kernel_launch(void* const* d_in, const int* in_sizes, int n_in,
                              void* d_out, int out_size, void* d_ws, size_t ws_size,
                              hipStream_t stream) {
  const float* X  = (const float*)d_in[0];   // [M,512] fp32
  const float* CB = (const float*)d_in[1];   // [K,512] fp32
  const int D = 512;
  const int M = in_sizes[0] / D;             // 16384
  const int K = in_sizes[1] / D;             // 2048
  float* out0 = (float*)d_out;               // quantized_ste [M,512]
  float* out1 = out0 + (size_t)M * D;        // loss          [M,512]
  float* out2 = out1 + (size_t)M * D;        // nn_idx (as f32) [M]
  float* out3 = out2 + M;                    // codebook copy [K,512]

  char* ws = (char*)d_ws;
  size_t off = 0;
  u16* Bpan = (u16*)(ws + off); off += (size_t)K * D * 2;     // f16 fragment panels
  float* c2 = (float*)(ws + off); off += (size_t)K * 4;
  float4* part = (float4*)(ws + off); off += (size_t)M * 32 * 16;
  u16* Apan = (u16*)(ws + off);
  const size_t need_big = off + (size_t)M * D * 2;
  const bool big = (ws_size >= need_big);

  vq_prep<<<K, 128, 0, stream>>>(CB, Bpan, c2, out3);
  const int nmt = M / 256, nnt = K / 256;                     // 64 x 8
  const int nwg = nmt * nnt;                                  // 512
  if (big) {
    vq_prep<<<M, 128, 0, stream>>>(X, Apan, nullptr, nullptr);
    vq_gemm<1><<<nwg, 512, 0, stream>>>(X, Apan, Bpan, c2, part, nnt);
  } else {
    vq_gemm<0><<<nwg, 512, 0, stream>>>(X, nullptr, Bpan, c2, part, nnt);
  }
  vq_final<<<M / 4, 256, 0, stream>>>(X, CB, part, out0, out1, out2);
}

// Round 14
// 94.137 us; speedup vs baseline: 1.0497x; 1.0479x over previous
//
#include <hip/hip_runtime.h>
#include <cfloat>

typedef unsigned short u16;
typedef unsigned int u32;
typedef u16   u16x4 __attribute__((ext_vector_type(4)));
typedef float f32x4 __attribute__((ext_vector_type(4)));
typedef _Float16 f16x8 __attribute__((ext_vector_type(8)));

#define GL2LDS(gp, lp) __builtin_amdgcn_global_load_lds(                      \
    (const __attribute__((address_space(1))) void*)(gp),                      \
    (__attribute__((address_space(3))) void*)(lp), 16, 0, 0)

// lexicographic (value, index) less — matches argmin lowest-index tie-break
__device__ __forceinline__ bool vless(float v, int i, float v2, int i2) {
  return v < v2 || (v == v2 && i < i2);
}

// monotonic float->uint map (order-preserving for all finite floats)
__device__ __forceinline__ u32 fmono(float f) {
  u32 u = __float_as_uint(f);
  return u ^ (0x80000000u | (u32)((int)u >> 31));
}
__device__ __forceinline__ float fmono_inv(u32 m) {
  u32 u = (m & 0x80000000u) ? (m ^ 0x80000000u) : ~m;
  return __uint_as_float(u);
}

// ---------------------------------------------------------------------------
// Pretile a [R,512] fp32 matrix into FRAGMENT-MAJOR f16 panels (+c2 +copy).
// Panel unit: (tile of 128 rows, 64-k slice s) = 16 KB; 16 fragments of 1 KB.
// Fragment (rb,h): rows rb*16..+15, k h*32..+31. Lane (kgrp*16+lrow) holds
// row lrow's k kgrp*8..+7 at frag_base + lane*16 — the exact MFMA operand
// order, so both gl2lds(B) and global_load_dwordx4(A) need zero shuffling.
__global__ __launch_bounds__(128) void vq_prep(
    const float* __restrict__ src, u16* __restrict__ pan,
    float* __restrict__ sq, float* __restrict__ copy_out) {
  __shared__ float red[2];
  const int row_g = blockIdx.x;
  const int t = threadIdx.x;             // 0..127, 4 floats each
  float4 v = reinterpret_cast<const float4*>(src + (size_t)row_g * 512)[t];
  if (copy_out)
    reinterpret_cast<float4*>(copy_out + (size_t)row_g * 512)[t] = v;
  float f[4] = {v.x, v.y, v.z, v.w};
  u16 q[4];
  #pragma unroll
  for (int i = 0; i < 4; ++i)
    q[i] = __builtin_bit_cast(u16, (_Float16)f[i]);   // RNE
  const int d = t * 4;
  const int tile = row_g >> 7, r = row_g & 127;
  const int rb = r >> 4, lrow = r & 15;
  const int s = d >> 6, kk = d & 63, h = kk >> 5, kkl = kk & 31;
  const int kgrp = kkl >> 3, e = kkl & 7;
  const size_t off = ((size_t)(tile * 8 + s)) * 16384 +
      (size_t)((rb * 2 + h) * 1024 + (kgrp * 16 + lrow) * 16 + e * 2);
  u16x4 tq = {q[0], q[1], q[2], q[3]};
  *reinterpret_cast<u16x4*>((char*)pan + off) = tq;
  if (sq) {
    float ssum = v.x*v.x + v.y*v.y + v.z*v.z + v.w*v.w;
    #pragma unroll
    for (int m = 1; m < 64; m <<= 1) ssum += __shfl_xor(ssum, m);
    if ((t & 63) == 0) red[t >> 6] = ssum;
    __syncthreads();
    if (t == 0) sq[row_g] = red[0] + red[1];
  }
}

// ---------------------------------------------------------------------------
// Screening GEMM + per-64-col-subtile TOP-2 (packed-key) argmin.
// Tile 128x128, 4 waves (2x2), per-wave 64x64, single f16 MFMA 16x16x32.
// A: global_load_dwordx4 from fragment-major f16 panel DIRECT to registers.
// B: fragment-major panel staged via gl2lds, double-buffered 2x16 KB,
//    ds_read at base+lane*16 (conflict-free), ONE __syncthreads per period.
// PHASE ROTATION (anti-herding): each block walks K-periods in order
// (s + bid) & 7 — co-resident blocks hit stage/MFMA phases at different
// times, so one block's staging is covered by neighbors' MFMA streams.
// score = c2[col] - 2*dot (x2 row-constant, dropped for argmin).
template <int PANEL_A>
__global__ __launch_bounds__(256, 4) void vq_gemm(
    const float* __restrict__ X,
    const u16* __restrict__ Apan, const u16* __restrict__ Bpan,
    const float* __restrict__ c2,
    float4* __restrict__ part, int nnt) {
  __shared__ u16 sB0[8192], sB1[8192];         // 16 KB + 16 KB
  const int tid = threadIdx.x;
  const int lane = tid & 63, wid = tid >> 6;   // 4 waves
  const int wm = wid >> 1, wn = wid & 1;       // 2 x 2
  const int nwg = gridDim.x;
  const int bid = blockIdx.x;
  const int swb = (bid & 7) * (nwg >> 3) + (bid >> 3);  // XCD band swizzle
  const int mtile = swb / nnt, ntile = swb % nnt;
  const int lrow = lane & 15, kgrp = lane >> 4;
  const int rot = bid & 7;                     // per-block period rotation
  f32x4 acc[4][4] = {};

  const char* gA = (const char*)Apan + ((size_t)mtile * 8) * 16384;
  const char* gB = (const char*)Bpan + ((size_t)ntile * 8) * 16384;
  // fallback: per-lane f32 row base (row = mtile*128 + wm*64 + t2*16 + lrow)
  const float* xbase =
      X + ((size_t)(mtile * 128 + wm * 64 + lrow)) * 512 + kgrp * 8;

  auto stageB = [&](int p, u16* dst) {         // stage period p's B half
    const char* g = gB + (size_t)p * 16384;
    #pragma unroll
    for (int i = 0; i < 4; ++i) {
      const int off = (wid * 4 + i) * 1024;    // wave-uniform LDS base
      GL2LDS(g + off + lane * 16, (char*)dst + off);
    }
  };

  // one K-period: compute period sp from `cur`, stage period np into `nxt`
  auto step = [&](int sp, int np, const u16* cur, u16* nxt) {
    f16x8 a[2][4];
    if constexpr (PANEL_A) {
      const char* ap = gA + (size_t)sp * 16384 + lane * 16;
      #pragma unroll
      for (int t2 = 0; t2 < 4; ++t2)
        #pragma unroll
        for (int h = 0; h < 2; ++h)
          a[h][t2] = *reinterpret_cast<const f16x8*>(
              ap + ((wm * 4 + t2) * 2 + h) * 1024);
    } else {
      const float* xp = xbase + sp * 64;
      #pragma unroll
      for (int t2 = 0; t2 < 4; ++t2)
        #pragma unroll
        for (int h = 0; h < 2; ++h) {
          const float4 f0 = *reinterpret_cast<const float4*>(xp + (size_t)t2 * 8192 + h * 32);
          const float4 f1 = *reinterpret_cast<const float4*>(xp + (size_t)t2 * 8192 + h * 32 + 4);
          f16x8 av;
          av[0] = (_Float16)f0.x; av[1] = (_Float16)f0.y;
          av[2] = (_Float16)f0.z; av[3] = (_Float16)f0.w;
          av[4] = (_Float16)f1.x; av[5] = (_Float16)f1.y;
          av[6] = (_Float16)f1.z; av[7] = (_Float16)f1.w;
          a[h][t2] = av;
        }
    }
    __syncthreads();           // buf(sp) visible; buf(np) safe to overwrite
    if (np >= 0) stageB(np, nxt);
    #pragma unroll
    for (int h = 0; h < 2; ++h) {
      __builtin_amdgcn_s_setprio(1);
      #pragma unroll
      for (int u = 0; u < 4; ++u) {
        const f16x8 b = *reinterpret_cast<const f16x8*>(
            (const char*)cur + ((wn * 4 + u) * 2 + h) * 1024 + lane * 16);
        #pragma unroll
        for (int i = 0; i < 4; ++i)
          acc[i][u] = __builtin_amdgcn_mfma_f32_16x16x32_f16(a[h][i], b, acc[i][u], 0, 0, 0);
      }
      __builtin_amdgcn_s_setprio(0);
    }
  };

  auto P = [&](int s) { return (s + rot) & 7; };
  stageB(P(0), sB0);
  #pragma unroll 1
  for (int it = 0; it < 4; ++it) {
    step(P(it * 2), P(it * 2 + 1), sB0, sB1);
    step(P(it * 2 + 1), (it < 3) ? P(it * 2 + 2) : -1, sB1, sB0);
  }

  // ---- epilogue: per-row TOP-2 over this wave's 64 cols via packed keys.
  // key = (monotonic(score) & ~0x7FF) | col. Quantization absorbed by the
  // final margin (1.0).
  float c2v[4];
  #pragma unroll
  for (int j = 0; j < 4; ++j) c2v[j] = c2[ntile * 128 + wn * 64 + j * 16 + lrow];
  #pragma unroll
  for (int i = 0; i < 4; ++i) {
    #pragma unroll
    for (int jj = 0; jj < 4; ++jj) {
      u32 k1 = 0xFFFFFFFFu, k2 = 0xFFFFFFFFu;
      #pragma unroll
      for (int j = 0; j < 4; ++j) {
        const float sc = c2v[j] - 2.0f * acc[i][j][jj];
        const u32 col = (u32)(ntile * 128 + wn * 64 + j * 16 + lrow);
        const u32 k = (fmono(sc) & 0xFFFFF800u) | col;
        if (k < k1) { k2 = k1; k1 = k; } else if (k < k2) { k2 = k; }
      }
      #pragma unroll
      for (int m = 1; m < 16; m <<= 1) {
        const u32 ok1 = (u32)__shfl_xor((int)k1, m);
        const u32 ok2 = (u32)__shfl_xor((int)k2, m);
        const u32 lo = min(k1, ok1), hi = max(k1, ok1);
        k1 = lo;
        k2 = min(hi, min(k2, ok2));
      }
      if (lrow == 0) {
        const int row = mtile * 128 + wm * 64 + i * 16 + kgrp * 4 + jj;
        part[(size_t)row * 32 + (ntile * 2 + wn)] =
            make_float4(fmono_inv(k1 & 0xFFFFF800u), __int_as_float((int)(k1 & 0x7FFu)),
                        fmono_inv(k2 & 0xFFFFF800u), __int_as_float((int)(k2 & 0x7FFu)));
      }
    }
  }
}

// ---------------------------------------------------------------------------
// Final: global approx argmin over 64 stored candidates/row; margin-flag;
// exact double-precision refine when >1 candidate within margin; outputs.
__global__ __launch_bounds__(256) void vq_final(
    const float* __restrict__ X, const float* __restrict__ CB,
    const float4* __restrict__ part,
    float* __restrict__ out0, float* __restrict__ out1, float* __restrict__ out2) {
  const int row = blockIdx.x * 4 + (threadIdx.x >> 6);
  const int l = threadIdx.x & 63;
  const float4 p = part[(size_t)row * 32 + (l >> 1)];
  const float v = (l & 1) ? p.z : p.x;
  const int ci = __float_as_int((l & 1) ? p.w : p.y);
  float rv = v; int ri = ci;
  #pragma unroll
  for (int m = 1; m < 64; m <<= 1) {
    const float ov = __shfl_xor(rv, m);
    const int oi = __shfl_xor(ri, m);
    if (vless(ov, oi, rv, ri)) { rv = ov; ri = oi; }
  }
  int idx;
  unsigned long long mask = __ballot(v <= rv + 1.0f);   // margin (f16 err + key quant)
  if (__popcll(mask) == 1) {
    idx = ri;                                            // certain winner
  } else {
    float xr[8];
    #pragma unroll
    for (int e = 0; e < 8; ++e) xr[e] = X[(size_t)row * 512 + l + e * 64];
    double bd = 1e300; int bi = 0x7fffffff;
    while (mask) {
      const int sl = __ffsll((long long)mask) - 1;
      mask &= mask - 1;
      const int cidx = __shfl(ci, sl);
      double accd = 0.0;
      #pragma unroll
      for (int e = 0; e < 8; ++e) {
        const double dd = (double)xr[e] - (double)CB[(size_t)cidx * 512 + l + e * 64];
        accd += dd * dd;
      }
      #pragma unroll
      for (int m = 1; m < 64; m <<= 1) accd += __shfl_xor(accd, m);
      if (accd < bd || (accd == bd && cidx < bi)) { bd = accd; bi = cidx; }
    }
    idx = bi;
  }
  const float4* xr4 = reinterpret_cast<const float4*>(X + (size_t)row * 512);
  const float4* cr4 = reinterpret_cast<const float4*>(CB + (size_t)idx * 512);
  float4* q  = reinterpret_cast<float4*>(out0 + (size_t)row * 512);
  float4* ls = reinterpret_cast<float4*>(out1 + (size_t)row * 512);
  #pragma unroll
  for (int pp = 0; pp < 2; ++pp) {
    const int e = l + 64 * pp;
    const float4 xv = xr4[e], cv = cr4[e];
    float4 d4, qv, lv;
    d4.x = cv.x - xv.x; d4.y = cv.y - xv.y; d4.z = cv.z - xv.z; d4.w = cv.w - xv.w;
    qv.x = xv.x + d4.x; qv.y = xv.y + d4.y; qv.z = xv.z + d4.z; qv.w = xv.w + d4.w;
    lv.x = d4.x * d4.x; lv.y = d4.y * d4.y; lv.z = d4.z * d4.z; lv.w = d4.w * d4.w;
    q[e] = qv; ls[e] = lv;
  }
  if (l == 0) out2[row] = (float)idx;
}

extern "C" void kernel_launch(void* const* d_in, const int* in_sizes, int n_in,
                              void* d_out, int out_size, void* d_ws, size_t ws_size,
                              hipStream_t stream) {
  const float* X  = (const float*)d_in[0];   // [M,512] fp32
  const float* CB = (const float*)d_in[1];   // [K,512] fp32
  const int D = 512;
  const int M = in_sizes[0] / D;             // 16384
  const int K = in_sizes[1] / D;             // 2048
  float* out0 = (float*)d_out;               // quantized_ste [M,512]
  float* out1 = out0 + (size_t)M * D;        // loss          [M,512]
  float* out2 = out1 + (size_t)M * D;        // nn_idx (as f32) [M]
  float* out3 = out2 + M;                    // codebook copy [K,512]

  char* ws = (char*)d_ws;
  size_t off = 0;
  u16* Bpan = (u16*)(ws + off); off += (size_t)K * D * 2;     // f16 fragment panels
  float* c2 = (float*)(ws + off); off += (size_t)K * 4;
  float4* part = (float4*)(ws + off); off += (size_t)M * 32 * 16;
  u16* Apan = (u16*)(ws + off);
  const size_t need_big = off + (size_t)M * D * 2;
  const bool big = (ws_size >= need_big);

  vq_prep<<<K, 128, 0, stream>>>(CB, Bpan, c2, out3);
  const int nmt = M / 128, nnt = K / 128;                     // 128 x 16
  const int nwg = nmt * nnt;                                  // 2048
  if (big) {
    vq_prep<<<M, 128, 0, stream>>>(X, Apan, nullptr, nullptr);
    vq_gemm<1><<<nwg, 256, 0, stream>>>(X, Apan, Bpan, c2, part, nnt);
  } else {
    vq_gemm<0><<<nwg, 256, 0, stream>>>(X, nullptr, Bpan, c2, part, nnt);
  }
  vq_final<<<M / 4, 256, 0, stream>>>(X, CB, part, out0, out1, out2);
}